// Round 3
// baseline (604.669 us; speedup 1.0000x reference)
//
#include <hip/hip_runtime.h>
#include <hip/hip_bf16.h>

// MultiExpertLoRALinear on MI355X.
// Round 3: latency-bound small kernels rebuilt; GEMM gets XCD swizzle (T1).
// Pipeline:
//   convert_w3    : wh[o][KP] fp16 = [W_base | Bcat | 0] (1 block/row, no idiv),
//                   vh[48][H] fp16 (lora_A rows, router_W rows, zero rows).
//   router_fused3 : per 16-token block: coalesced x read -> reg fp16 convert ->
//                   (a) coalesced xh main-col write, (b) swizzled LDS tile ->
//                   MFMA z[16][48] vs LDS-staged vh chunks (kk-split 4 waves) ->
//                   cross-wave reduce -> softmax -> c cols + zero pad of xh.
//   gemm          : fp16 MFMA GEMM [M, O, KP=4160], 128x128 tile, BK=64,
//                   global_load_lds + XOR-swizzle (0 bank conflicts measured),
//                   + XCD-aware blockIdx swizzle.

typedef _Float16 f16x8 __attribute__((ext_vector_type(8)));
typedef float    f32x4 __attribute__((ext_vector_type(4)));

constexpr int H  = 4096;
constexpr int O  = 4096;
constexpr int KP = 4160;   // 4096 + 32 (c cols) + 32 zero pad
constexpr int EA = 4;
constexpr float SCALING_F = 2.0f;  // alpha/rank

typedef const __attribute__((address_space(1))) void gvoid;
typedef __attribute__((address_space(3))) void svoid;

__device__ inline void gload16(const void* g, void* s) {
  __builtin_amdgcn_global_load_lds((gvoid*)g, (svoid*)s, 16, 0, 0);
}

// ---------------------------------------------------------------------------
// Kernel 1: build wh and vh. Block o < O: wh row o (520 groups of 8).
//           Block O+j (j<48): vh row j (512 groups of 8).
// ---------------------------------------------------------------------------
__global__ __launch_bounds__(256) void convert_w3_kernel(
    const float* __restrict__ W, const float* __restrict__ lora_B,
    const float* __restrict__ lora_A, const float* __restrict__ router_W,
    const int* __restrict__ active, _Float16* __restrict__ wh,
    _Float16* __restrict__ vh) {
  const int bid = blockIdx.x;
  const int tid = threadIdx.x;
  if (bid < O) {
    const int o = bid;
    const float* wrow = W + (size_t)o * H;
    _Float16* dstrow = wh + (size_t)o * KP;
    for (int g = tid; g < 520; g += 256) {
      const int k = g * 8;
      float v[8];
      if (k < H) {
        float4 a = *(const float4*)(wrow + k), b = *(const float4*)(wrow + k + 4);
        v[0] = a.x; v[1] = a.y; v[2] = a.z; v[3] = a.w;
        v[4] = b.x; v[5] = b.y; v[6] = b.z; v[7] = b.w;
      } else if (k < H + 32) {
        const int e = (k - H) >> 3;
        const float* s = lora_B + ((size_t)active[e] * O + o) * 8;  // [E,O,r]
        float4 a = *(const float4*)s, b = *(const float4*)(s + 4);
        v[0] = a.x; v[1] = a.y; v[2] = a.z; v[3] = a.w;
        v[4] = b.x; v[5] = b.y; v[6] = b.z; v[7] = b.w;
      } else {
#pragma unroll
        for (int i = 0; i < 8; ++i) v[i] = 0.f;
      }
      f16x8 h;
#pragma unroll
      for (int i = 0; i < 8; ++i) h[i] = (_Float16)v[i];
      *(f16x8*)(dstrow + k) = h;
    }
  } else {
    const int j = bid - O;          // 0..47
    const float* src = nullptr;
    if (j < 32)      src = lora_A + (size_t)(active[j >> 3] * 8 + (j & 7)) * H;
    else if (j < 36) src = router_W + (size_t)active[j - 32] * H;
    _Float16* dstrow = vh + (size_t)j * H;
    for (int g = tid; g < 512; g += 256) {
      const int k = g * 8;
      f16x8 h;
      if (src) {
        float4 a = *(const float4*)(src + k), b = *(const float4*)(src + k + 4);
        h[0] = (_Float16)a.x; h[1] = (_Float16)a.y;
        h[2] = (_Float16)a.z; h[3] = (_Float16)a.w;
        h[4] = (_Float16)b.x; h[5] = (_Float16)b.y;
        h[6] = (_Float16)b.z; h[7] = (_Float16)b.w;
      } else {
#pragma unroll
        for (int i = 0; i < 8; ++i) h[i] = (_Float16)0.f;
      }
      *(f16x8*)(dstrow + k) = h;
    }
  }
}

// ---------------------------------------------------------------------------
// Kernel 2: fused convert_x + router + c-columns, GEMM-style staging.
// 256 thr = 4 waves, 16 tokens/block, K-chunks of 128.
// Thread tid: row=tid>>4, c8=tid&15 (8 floats). Coalesced x read, reg convert,
// coalesced xh write, swizzled ds_write As[row][c8^row]. V chunk staged via
// gload16 with pre-swizzled source. Wave w does kk=w: 3 MFMAs -> acc[3].
// ---------------------------------------------------------------------------
constexpr int TM = 16, KC = 128, NCH = H / KC;   // 32 chunks

__global__ __launch_bounds__(256) void router_fused3_kernel(
    const float* __restrict__ x, const _Float16* __restrict__ vh,
    const float* __restrict__ router_b, const float* __restrict__ prior,
    const int* __restrict__ active, _Float16* __restrict__ xh) {
  __shared__ _Float16 As[TM * KC];     // row*128 + slot(16B units)*8, slot^=row
  __shared__ _Float16 Vs[48 * KC];     // same swizzle
  __shared__ float zred[4][TM][48];
  const int tid  = threadIdx.x;
  const int lane = tid & 63;
  const int w    = tid >> 6;
  const long t0  = (long)blockIdx.x * TM;
  const int row  = tid >> 4;           // 0..15 token row (staging role)
  const int c8   = tid & 15;           // 8-float group (staging role)
  const int r15  = lane & 15;          // frag row
  const int kg   = lane >> 4;          // frag k-group

  const float* xrow = x + (t0 + row) * H + c8 * 8;
  _Float16*    xhrow = xh + (t0 + row) * KP + c8 * 8;
  _Float16*    asdst = As + row * KC + (c8 ^ row) * 8;

  f32x4 acc[3];
  const f32x4 zero = {0.f, 0.f, 0.f, 0.f};
  acc[0] = zero; acc[1] = zero; acc[2] = zero;

  // x prefetch regs (chunk 0)
  float4 xa = *(const float4*)(xrow);
  float4 xb = *(const float4*)(xrow + 4);

  for (int t = 0; t < NCH; ++t) {
    const int k0 = t * KC;
    float4 na, nb;
    if (t + 1 < NCH) {                 // prefetch next chunk
      na = *(const float4*)(xrow + k0 + KC);
      nb = *(const float4*)(xrow + k0 + KC + 4);
    }
    __syncthreads();                   // LDS safe to overwrite
    // stage A (convert + LDS + xh), stage V (gload16, pre-swizzled src)
    f16x8 h;
    h[0] = (_Float16)xa.x; h[1] = (_Float16)xa.y;
    h[2] = (_Float16)xa.z; h[3] = (_Float16)xa.w;
    h[4] = (_Float16)xb.x; h[5] = (_Float16)xb.y;
    h[6] = (_Float16)xb.z; h[7] = (_Float16)xb.w;
    *(f16x8*)asdst = h;
    *(f16x8*)(xhrow + k0) = h;
#pragma unroll
    for (int j = 0; j < 3; ++j) {
      const int sv   = tid + 256 * j;  // 0..767 slot id
      const int vrow = sv >> 4;
      const int vs8  = sv & 15;
      gload16(vh + (size_t)vrow * H + k0 + ((vs8 ^ (vrow & 15)) * 8),
              Vs + sv * 8);
    }
    __syncthreads();                   // stage complete (vmcnt+lgkm drained)
    // MFMA: wave w handles k-offset w*32 within chunk
    const int slot = ((w * 4 + kg) ^ r15) * 8;
    f16x8 a = *(const f16x8*)(As + r15 * KC + slot);
#pragma unroll
    for (int nf = 0; nf < 3; ++nf) {
      const int vr = nf * 16 + r15;
      f16x8 b = *(const f16x8*)(Vs + vr * KC + (((w * 4 + kg) ^ (vr & 15)) * 8));
      acc[nf] = __builtin_amdgcn_mfma_f32_16x16x32_f16(a, b, acc[nf], 0, 0, 0);
    }
    xa = na; xb = nb;
  }

  // scatter partials: C/D layout col=lane&15 (j), row=(lane>>4)*4+r (token)
#pragma unroll
  for (int nf = 0; nf < 3; ++nf)
#pragma unroll
    for (int r = 0; r < 4; ++r)
      zred[w][kg * 4 + r][nf * 16 + r15] = acc[nf][r];
  __syncthreads();

  // reduce 4 partials: 16*48=768 slots, 3 per thread
  float s[3];
#pragma unroll
  for (int j = 0; j < 3; ++j) {
    const int sl = tid + 256 * j;
    const int tt = sl / 48, jj = sl % 48;
    s[j] = zred[0][tt][jj] + zred[1][tt][jj] + zred[2][tt][jj] + zred[3][tt][jj];
  }
  __syncthreads();
#pragma unroll
  for (int j = 0; j < 3; ++j) {
    const int sl = tid + 256 * j;
    zred[0][sl / 48][sl % 48] = s[j];
  }
  __syncthreads();

  // softmax + c-columns + zero pad: thread = (token t, expert e)
  if (tid < TM * EA) {
    const int tt = tid >> 2, e = tid & 3;
    const float* zt = &zred[0][tt][0];
    float le[EA], mx = -1e30f;
#pragma unroll
    for (int e2 = 0; e2 < EA; ++e2) {
      const int ae = active[e2];
      le[e2] = logf(prior[ae] + 1e-12f) + zt[32 + e2] + router_b[ae];
      mx = fmaxf(mx, le[e2]);
    }
    float sum = 0.f;
#pragma unroll
    for (int e2 = 0; e2 < EA; ++e2) sum += expf(le[e2] - mx);
    const float a = expf(le[e] - mx) / sum * SCALING_F;
    f16x8 ch, zz;
#pragma unroll
    for (int r = 0; r < 8; ++r) {
      ch[r] = (_Float16)(a * zt[e * 8 + r]);
      zz[r] = (_Float16)0.f;
    }
    _Float16* xr = xh + (t0 + tt) * KP + H;
    *(f16x8*)(xr + e * 8) = ch;
    *(f16x8*)(xr + 32 + e * 8) = zz;
  }
}

// ---------------------------------------------------------------------------
// Kernel 3: fp16 MFMA GEMM. out[t][o] = sum_k xh[t][k]*wh[o][k] + b_base[o].
// 128x128 tile, BK=64, 4 waves x (64x64), XOR-swizzled LDS (0 conflicts),
// global_load_lds staging, XCD-aware block swizzle (grid 2048 % 8 == 0).
// ---------------------------------------------------------------------------
constexpr int BM = 128, BN = 128, BK = 64;

__global__ __launch_bounds__(256) void gemm_kernel(
    const _Float16* __restrict__ xh, const _Float16* __restrict__ wh,
    const float* __restrict__ b_base, float* __restrict__ out) {
  __shared__ _Float16 As[BM * BK];
  __shared__ _Float16 Ws[BN * BK];
  const int tid  = threadIdx.x;
  const int lane = tid & 63;
  const int wave = tid >> 6;
  // XCD swizzle: 8 XCDs, contiguous 256-block chunk per XCD
  const int bid = (int)blockIdx.x;
  const int swz = (bid & 7) * 256 + (bid >> 3);
  const int im = swz >> 5;                 // 64 M-tiles
  const int in = swz & 31;                 // 32 N-tiles
  const size_t trow0 = (size_t)im * BM;
  const size_t ocol0 = (size_t)in * BN;
  const int wr = wave >> 1, wc = wave & 1;

  f32x4 acc[4][4];
  const f32x4 zero = {0.f, 0.f, 0.f, 0.f};
#pragma unroll
  for (int m = 0; m < 4; ++m)
#pragma unroll
    for (int n = 0; n < 4; ++n) acc[m][n] = zero;

  const int srow  = lane >> 3;
  const int sslot = (lane & 7) ^ srow;
  const int r15 = lane & 15;
  const int kg  = lane >> 4;

  for (int step = 0; step < KP / BK; ++step) {
    const int k0 = step * BK;
    __syncthreads();
#pragma unroll
    for (int i = 0; i < 8; ++i) {
      const int ch  = wave + 4 * i;
      const int sub = ch & 15;
      const int row = sub * 8 + srow;
      if (ch < 16)
        gload16(xh + (trow0 + row) * KP + k0 + sslot * 8, As + sub * 512);
      else
        gload16(wh + (ocol0 + row) * KP + k0 + sslot * 8, Ws + sub * 512);
    }
    __syncthreads();
#pragma unroll
    for (int kk = 0; kk < 2; ++kk) {
      f16x8 a[4], b[4];
#pragma unroll
      for (int m = 0; m < 4; ++m) {
        const int row  = wr * 64 + m * 16 + r15;
        const int slot = (kk * 4 + kg) ^ (row & 7);
        a[m] = *(const f16x8*)(As + row * 64 + slot * 8);
      }
#pragma unroll
      for (int n = 0; n < 4; ++n) {
        const int row  = wc * 64 + n * 16 + r15;
        const int slot = (kk * 4 + kg) ^ (row & 7);
        b[n] = *(const f16x8*)(Ws + row * 64 + slot * 8);
      }
#pragma unroll
      for (int m = 0; m < 4; ++m)
#pragma unroll
        for (int n = 0; n < 4; ++n)
          acc[m][n] = __builtin_amdgcn_mfma_f32_16x16x32_f16(a[m], b[n], acc[m][n], 0, 0, 0);
    }
  }
#pragma unroll
  for (int n = 0; n < 4; ++n) {
    const size_t col = ocol0 + wc * 64 + n * 16 + r15;
    const float bb = b_base[col];
#pragma unroll
    for (int m = 0; m < 4; ++m) {
      const size_t row = trow0 + wr * 64 + m * 16 + kg * 4;
#pragma unroll
      for (int j = 0; j < 4; ++j)
        out[(row + j) * O + col] = acc[m][n][j] + bb;
    }
  }
}

// ---------------------------------------------------------------------------
extern "C" void kernel_launch(void* const* d_in, const int* in_sizes, int n_in,
                              void* d_out, int out_size, void* d_ws, size_t ws_size,
                              hipStream_t stream) {
  const float* x        = (const float*)d_in[0];
  const float* W_base   = (const float*)d_in[1];
  const float* b_base   = (const float*)d_in[2];
  const float* lora_A   = (const float*)d_in[3];
  const float* lora_B   = (const float*)d_in[4];
  const float* router_W = (const float*)d_in[5];
  const float* router_b = (const float*)d_in[6];
  const float* prior    = (const float*)d_in[7];
  const int*   active   = (const int*)d_in[8];
  float* out = (float*)d_out;

  const int M = in_sizes[0] / H;  // 8192 tokens

  char* ws = (char*)d_ws;
  _Float16* xh = (_Float16*)ws;                               // M*KP*2  = 68.2 MB
  _Float16* wh = (_Float16*)(ws + (size_t)M * KP * 2);        // O*KP*2  = 34.1 MB
  _Float16* vh = (_Float16*)(ws + (size_t)M * KP * 2 + (size_t)O * KP * 2);  // 384 KB

  convert_w3_kernel<<<O + 48, 256, 0, stream>>>(W_base, lora_B, lora_A, router_W,
                                                active, wh, vh);
  router_fused3_kernel<<<M / TM, 256, 0, stream>>>(x, vh, router_b, prior, active, xh);
  gemm_kernel<<<(M / BM) * (O / BN), 256, 0, stream>>>(xh, wh, b_base, out);
}